// Round 5
// baseline (1511.687 us; speedup 1.0000x reference)
//
#include <hip/hip_runtime.h>
#include <math.h>

#define E_N 19
#define H_N 32
#define T_N 2048
#define B_N 64
#define G_N 128      // 4*H gate rows per chain
#define XCHUNK 64    // timesteps staged per register round

__device__ __forceinline__ float lanef(float v, int l) {
    return __int_as_float(__builtin_amdgcn_readlane(__float_as_int(v), l));
}

// One WAVE (one 64-thread block) per chain (b, e, dir). Zero LDS, zero barriers.
// Lane pairing: j = lane&31, half = lane>>5.
//   half0 lane j owns gate rows i_j (row j)    and f_j (row j+32)  [sigmoid, sigmoid]
//   half1 lane j owns gate rows g_j (row j+64) and o_j (row j+96)  [tanh,    sigmoid]
// h broadcast: 32 v_readlane -> SGPRs; x broadcast: 1 register/lane + readlane.
// amdgpu_waves_per_eu(3,3): pin the allocator's occupancy TARGET (not just cap)
// so 64 resident weight VGPRs are free (168 budget) and remat/spill has no payoff.
__global__ __launch_bounds__(64)
__attribute__((amdgpu_waves_per_eu(3, 3)))
void lstm_chain_kernel(
    const float* __restrict__ x,     // [B, T, E]
    const float* __restrict__ w_ih,  // [E, 2, 4H]
    const float* __restrict__ w_hh,  // [E, 2, 4H, H]
    const float* __restrict__ b_ih,  // [E, 2, 4H]
    const float* __restrict__ b_hh,  // [E, 2, 4H]
    float* __restrict__ hT)          // [B, E, 2, H]
{
    const int lane  = threadIdx.x;
    const int chain = blockIdx.x;            // b*(E*2) + e*2 + d
    const int b  = chain / (E_N * 2);
    const int ed = chain - b * (E_N * 2);
    const int e  = ed >> 1;
    const int d  = ed & 1;
    const int j    = lane & 31;
    const int half = lane >> 5;

    const int r1 = j + 64 * half;        // i_j or g_j
    const int r2 = j + 32 + 64 * half;   // f_j or o_j

    // ---- load weights into registers ----
    const float* wr1 = w_hh + ((size_t)ed * G_N + r1) * H_N;
    const float* wr2 = w_hh + ((size_t)ed * G_N + r2) * H_N;
    float w1[H_N], w2[H_N];
    #pragma unroll
    for (int k = 0; k < H_N; k += 4) {
        float4 v1 = *(const float4*)(wr1 + k);
        float4 v2 = *(const float4*)(wr2 + k);
        w1[k+0]=v1.x; w1[k+1]=v1.y; w1[k+2]=v1.z; w1[k+3]=v1.w;
        w2[k+0]=v2.x; w2[k+1]=v2.y; w2[k+2]=v2.z; w2[k+3]=v2.w;
    }

    const float wih1  = w_ih[(size_t)ed * G_N + r1];
    const float wih2  = w_ih[(size_t)ed * G_N + r2];
    const float bias1 = b_ih[(size_t)ed * G_N + r1] + b_hh[(size_t)ed * G_N + r1];
    const float bias2 = b_ih[(size_t)ed * G_N + r2] + b_hh[(size_t)ed * G_N + r2];

    // act1: half0 -> sigmoid(x)=1/(1+e^-x); half1 -> tanh(x)=2/(1+e^-2x)-1
    const float S1 = half ? -2.0f : -1.0f;
    const float A1 = half ?  2.0f :  1.0f;
    const float B1 = half ? -1.0f :  0.0f;

    float sh[H_N];   // wave-uniform h broadcast (readlane results -> SGPRs)
    #pragma unroll
    for (int k = 0; k < H_N; ++k) sh[k] = 0.0f;

    float c = 0.0f;
    float h = 0.0f;

    const float* xbase = x + (size_t)b * T_N * E_N + e;

    for (int t0 = 0; t0 < T_N; t0 += XCHUNK) {
        // PIN: keep all 64 weight floats live in VGPRs across the inner loop
        // (runtime no-op; blocks load-sinking into the step loop).
        #pragma unroll
        for (int k = 0; k < H_N; ++k) {
            asm volatile("" : "+v"(w1[k]), "+v"(w2[k]));
        }

        // stage 64 timesteps, one per lane (reversed time for d==1)
        const int tt    = t0 + lane;
        const int tphys = d ? (T_N - 1 - tt) : tt;
        const float xr  = xbase[(size_t)tphys * E_N];

        #pragma unroll 1
        for (int tl = 0; tl < XCHUNK; ++tl) {
            const float sx = lanef(xr, tl);          // wave-uniform x_t

            float a1 = fmaf(sx, wih1, bias1), a1b = 0.0f;
            float a2 = fmaf(sx, wih2, bias2), a2b = 0.0f;
            #pragma unroll
            for (int k = 0; k < H_N; k += 2) {
                a1  = fmaf(sh[k],   w1[k],   a1);
                a1b = fmaf(sh[k+1], w1[k+1], a1b);
                a2  = fmaf(sh[k],   w2[k],   a2);
                a2b = fmaf(sh[k+1], w2[k+1], a2b);
            }
            const float g1 = a1 + a1b;
            const float g2 = a2 + a2b;

            // act1: sigmoid (half0) / tanh (half1); act2: sigmoid (both)
            const float act1 = fmaf(A1, __fdividef(1.0f, 1.0f + __expf(S1 * g1)), B1);
            const float act2 = __fdividef(1.0f, 1.0f + __expf(-g2));

            const float oth1 = __shfl_xor(act1, 32); // half0 gets g_j ; half1 gets i_j
            const float oth2 = __shfl_xor(act2, 32); // half0 gets o_j ; half1 gets f_j

            const float ig = act1 * oth1;            // i_j * g_j on both halves
            const float fv = half ? oth2 : act2;     // f_j
            const float ov = half ? act2 : oth2;     // o_j

            c = fmaf(fv, c, ig);
            const float tc = fmaf(2.0f, __fdividef(1.0f, 1.0f + __expf(-2.0f * c)), -1.0f);
            h = ov * tc;

            #pragma unroll
            for (int k = 0; k < H_N; ++k) sh[k] = lanef(h, k);
        }
    }

    if (!half) {
        hT[((size_t)(b * E_N + e) * 2 + d) * H_N + j] = h;
    }
}

// LayerNorm over 64 feats per (b,e), mean over e, FC -> out[b]. One wave per b.
__global__ __launch_bounds__(64) void head_kernel(
    const float* __restrict__ hT,      // [B, E, 64]
    const float* __restrict__ ln_gamma,// [E, 64]
    const float* __restrict__ ln_beta, // [E, 64]
    const float* __restrict__ fc_w,    // [64]
    const float* __restrict__ fc_b,    // [1]
    float* __restrict__ out)           // [B]
{
    const int b = blockIdx.x;
    const int f = threadIdx.x; // 0..63

    float acc = 0.0f;
    for (int e = 0; e < E_N; ++e) {
        const float v = hT[(size_t)(b * E_N + e) * 64 + f];
        float s = v, s2 = v * v;
        #pragma unroll
        for (int off = 32; off > 0; off >>= 1) {
            s  += __shfl_xor(s,  off);
            s2 += __shfl_xor(s2, off);
        }
        const float mean = s * (1.0f / 64.0f);
        const float var  = s2 * (1.0f / 64.0f) - mean * mean;
        const float inv  = rsqrtf(var + 1e-5f);
        acc += (v - mean) * inv * ln_gamma[e * 64 + f] + ln_beta[e * 64 + f];
    }
    float contrib = (acc * (1.0f / (float)E_N)) * fc_w[f];
    #pragma unroll
    for (int off = 32; off > 0; off >>= 1) contrib += __shfl_xor(contrib, off);
    if (f == 0) out[b] = contrib + fc_b[0];
}

extern "C" void kernel_launch(void* const* d_in, const int* in_sizes, int n_in,
                              void* d_out, int out_size, void* d_ws, size_t ws_size,
                              hipStream_t stream) {
    const float* x        = (const float*)d_in[0];
    const float* w_ih     = (const float*)d_in[1];
    const float* w_hh     = (const float*)d_in[2];
    const float* b_ih     = (const float*)d_in[3];
    const float* b_hh     = (const float*)d_in[4];
    const float* ln_gamma = (const float*)d_in[5];
    const float* ln_beta  = (const float*)d_in[6];
    const float* fc_w     = (const float*)d_in[7];
    const float* fc_b     = (const float*)d_in[8];
    float* out = (float*)d_out;
    float* hT  = (float*)d_ws;  // B*E*2*H floats

    lstm_chain_kernel<<<B_N * E_N * 2, 64, 0, stream>>>(x, w_ih, w_hh, b_ih, b_hh, hT);
    head_kernel<<<B_N, 64, 0, stream>>>(hT, ln_gamma, ln_beta, fc_w, fc_b, out);
}

// Round 6
// 1104.415 us; speedup vs baseline: 1.3688x; 1.3688x over previous
//
#include <hip/hip_runtime.h>
#include <math.h>
#include <stdint.h>

#define E_N 19
#define H_N 32
#define T_N 2048
#define B_N 64
#define G_N 128      // 4*H gate rows per chain
#define XCHUNK 64    // timesteps staged per register round
#define LOG2E 1.4426950408889634f

typedef _Float16 half2_t __attribute__((ext_vector_type(2)));

__device__ __forceinline__ float lanef(float v, int l) {
    return __int_as_float(__builtin_amdgcn_readlane(__float_as_int(v), l));
}
__device__ __forceinline__ uint32_t laneu(uint32_t v, int l) {
    return (uint32_t)__builtin_amdgcn_readlane((int)v, l);
}
__device__ __forceinline__ float sigm_rcp(float e) {  // 1/(1+e)
    return __builtin_amdgcn_rcpf(1.0f + e);
}

// One WAVE per chain (b, e, dir). Zero LDS, zero barriers.
// Lane pairing: j = lane&31, half = lane>>5.
//   half0 lane j owns gate rows i_j (row j)    and f_j (row j+32)  [sigmoid, sigmoid]
//   half1 lane j owns gate rows g_j (row j+64) and o_j (row j+96)  [tanh,    sigmoid]
// Weights held as 32 packed fp16-pair VGPRs (v_dot2_f32_f16, fp32 accumulate);
// h broadcast as 16 packed fp16-pair SGPRs via readlane. x, c, biases, acts fp32.
__global__ __launch_bounds__(64)
__attribute__((amdgpu_waves_per_eu(3, 3)))
void lstm_chain_kernel(
    const float* __restrict__ x,     // [B, T, E]
    const float* __restrict__ w_ih,  // [E, 2, 4H]
    const float* __restrict__ w_hh,  // [E, 2, 4H, H]
    const float* __restrict__ b_ih,  // [E, 2, 4H]
    const float* __restrict__ b_hh,  // [E, 2, 4H]
    float* __restrict__ hT)          // [B, E, 2, H]
{
    const int lane  = threadIdx.x;
    const int chain = blockIdx.x;            // b*(E*2) + e*2 + d
    const int b  = chain / (E_N * 2);
    const int ed = chain - b * (E_N * 2);
    const int e  = ed >> 1;
    const int d  = ed & 1;
    const int j    = lane & 31;
    const int half = lane >> 5;

    const int r1 = j + 64 * half;        // i_j or g_j
    const int r2 = j + 32 + 64 * half;   // f_j or o_j

    // ---- load fp32 weights, quantize to packed fp16 pairs (16+16 VGPRs) ----
    const float* wr1 = w_hh + ((size_t)ed * G_N + r1) * H_N;
    const float* wr2 = w_hh + ((size_t)ed * G_N + r2) * H_N;
    uint32_t w1p[16], w2p[16];
    #pragma unroll
    for (int m = 0; m < 16; ++m) {
        float2 v1 = ((const float2*)wr1)[m];
        float2 v2 = ((const float2*)wr2)[m];
        half2_t p1 = { (_Float16)v1.x, (_Float16)v1.y };
        half2_t p2 = { (_Float16)v2.x, (_Float16)v2.y };
        w1p[m] = __builtin_bit_cast(uint32_t, p1);
        w2p[m] = __builtin_bit_cast(uint32_t, p2);
    }

    const float wih1  = w_ih[(size_t)ed * G_N + r1];
    const float wih2  = w_ih[(size_t)ed * G_N + r2];
    const float bias1 = b_ih[(size_t)ed * G_N + r1] + b_hh[(size_t)ed * G_N + r1];
    const float bias2 = b_ih[(size_t)ed * G_N + r2] + b_hh[(size_t)ed * G_N + r2];

    // act1: half0 -> sigmoid(g)=1/(1+2^(-g*log2e)); half1 -> tanh(g)=2/(1+2^(-2g*log2e))-1
    const float K1 = half ? (-2.0f * LOG2E) : (-LOG2E);
    const float A1 = half ?  2.0f :  1.0f;
    const float B1 = half ? -1.0f :  0.0f;

    uint32_t sh[16];   // wave-uniform packed h pairs (readlane -> SGPRs)
    #pragma unroll
    for (int m = 0; m < 16; ++m) sh[m] = 0u;

    float c = 0.0f;
    float h = 0.0f;

    const float* xbase = x + (size_t)b * T_N * E_N + e;

    for (int t0 = 0; t0 < T_N; t0 += XCHUNK) {
        // PIN: keep the 32 packed weight regs live across the inner loop (no-op).
        #pragma unroll
        for (int m = 0; m < 16; ++m) {
            asm volatile("" : "+v"(w1p[m]), "+v"(w2p[m]));
        }

        // stage 64 timesteps, one per lane (reversed time for d==1)
        const int tt    = t0 + lane;
        const int tphys = d ? (T_N - 1 - tt) : tt;
        const float xr  = xbase[(size_t)tphys * E_N];

        #pragma unroll 1
        for (int tl = 0; tl < XCHUNK; ++tl) {
            const float sx = lanef(xr, tl);          // wave-uniform x_t

            float a1 = fmaf(sx, wih1, bias1), a1b = 0.0f;
            float a2 = fmaf(sx, wih2, bias2), a2b = 0.0f;
            #pragma unroll
            for (int m = 0; m < 8; ++m) {
                a1  = __builtin_amdgcn_fdot2(__builtin_bit_cast(half2_t, sh[m]),
                                             __builtin_bit_cast(half2_t, w1p[m]),   a1,  false);
                a1b = __builtin_amdgcn_fdot2(__builtin_bit_cast(half2_t, sh[m+8]),
                                             __builtin_bit_cast(half2_t, w1p[m+8]), a1b, false);
                a2  = __builtin_amdgcn_fdot2(__builtin_bit_cast(half2_t, sh[m]),
                                             __builtin_bit_cast(half2_t, w2p[m]),   a2,  false);
                a2b = __builtin_amdgcn_fdot2(__builtin_bit_cast(half2_t, sh[m+8]),
                                             __builtin_bit_cast(half2_t, w2p[m+8]), a2b, false);
            }
            const float g1 = a1 + a1b;
            const float g2 = a2 + a2b;

            // act1: sigmoid (half0) / tanh (half1); act2: sigmoid (both)
            const float e1   = __builtin_amdgcn_exp2f(g1 * K1);
            const float act1 = fmaf(A1, sigm_rcp(e1), B1);
            const float e2   = __builtin_amdgcn_exp2f(g2 * (-LOG2E));
            const float act2 = sigm_rcp(e2);

            const float oth1 = __shfl_xor(act1, 32); // half0 gets g_j ; half1 gets i_j
            const float oth2 = __shfl_xor(act2, 32); // half0 gets o_j ; half1 gets f_j

            const float ig = act1 * oth1;            // i_j * g_j on both halves
            const float fv = half ? oth2 : act2;     // f_j
            const float ov = half ? act2 : oth2;     // o_j

            c = fmaf(fv, c, ig);
            const float ec = __builtin_amdgcn_exp2f(c * (-2.0f * LOG2E));
            const float tc = fmaf(2.0f, sigm_rcp(ec), -1.0f);   // tanh(c)
            h = ov * tc;

            // pack h pairs: lane 2m builds (h_2m, h_2m+1); 16 readlanes -> SGPRs
            const _Float16 hh = (_Float16)h;
            const uint32_t hlo = (uint32_t)__builtin_bit_cast(uint16_t, hh);
            const uint32_t nb  = (uint32_t)__shfl_down((int)hlo, 1);
            const uint32_t pk  = hlo | (nb << 16);
            #pragma unroll
            for (int m = 0; m < 16; ++m) sh[m] = laneu(pk, 2 * m);
        }
    }

    if (!half) {
        hT[((size_t)(b * E_N + e) * 2 + d) * H_N + j] = h;
    }
}

// LayerNorm over 64 feats per (b,e), mean over e, FC -> out[b]. One wave per b.
__global__ __launch_bounds__(64) void head_kernel(
    const float* __restrict__ hT,      // [B, E, 64]
    const float* __restrict__ ln_gamma,// [E, 64]
    const float* __restrict__ ln_beta, // [E, 64]
    const float* __restrict__ fc_w,    // [64]
    const float* __restrict__ fc_b,    // [1]
    float* __restrict__ out)           // [B]
{
    const int b = blockIdx.x;
    const int f = threadIdx.x; // 0..63

    float acc = 0.0f;
    for (int e = 0; e < E_N; ++e) {
        const float v = hT[(size_t)(b * E_N + e) * 64 + f];
        float s = v, s2 = v * v;
        #pragma unroll
        for (int off = 32; off > 0; off >>= 1) {
            s  += __shfl_xor(s,  off);
            s2 += __shfl_xor(s2, off);
        }
        const float mean = s * (1.0f / 64.0f);
        const float var  = s2 * (1.0f / 64.0f) - mean * mean;
        const float inv  = rsqrtf(var + 1e-5f);
        acc += (v - mean) * inv * ln_gamma[e * 64 + f] + ln_beta[e * 64 + f];
    }
    float contrib = (acc * (1.0f / (float)E_N)) * fc_w[f];
    #pragma unroll
    for (int off = 32; off > 0; off >>= 1) contrib += __shfl_xor(contrib, off);
    if (f == 0) out[b] = contrib + fc_b[0];
}

extern "C" void kernel_launch(void* const* d_in, const int* in_sizes, int n_in,
                              void* d_out, int out_size, void* d_ws, size_t ws_size,
                              hipStream_t stream) {
    const float* x        = (const float*)d_in[0];
    const float* w_ih     = (const float*)d_in[1];
    const float* w_hh     = (const float*)d_in[2];
    const float* b_ih     = (const float*)d_in[3];
    const float* b_hh     = (const float*)d_in[4];
    const float* ln_gamma = (const float*)d_in[5];
    const float* ln_beta  = (const float*)d_in[6];
    const float* fc_w     = (const float*)d_in[7];
    const float* fc_b     = (const float*)d_in[8];
    float* out = (float*)d_out;
    float* hT  = (float*)d_ws;  // B*E*2*H floats

    lstm_chain_kernel<<<B_N * E_N * 2, 64, 0, stream>>>(x, w_ih, w_hh, b_ih, b_hh, hT);
    head_kernel<<<B_N, 64, 0, stream>>>(hT, ln_gamma, ln_beta, fc_w, fc_b, out);
}